// Round 5
// baseline (1710.552 us; speedup 1.0000x reference)
//
#include <hip/hip_runtime.h>
#include <cstdint>

// ---------------- problem constants ----------------
#define NPOS 8192              // 8*32*32 spatial positions
#define KTOT 6912              // 27 taps * 256 channels
#define XP_ROWS 11560          // 10*34*34 padded spatial rows
#define XP_SY 34
#define XP_SZ 1156             // 34*34
#define KS 6                   // K-splits
#define KSL 1152               // KTOT/KS (18 chunks of 64)

typedef float  facc_t __attribute__((ext_vector_type(4)));
typedef short  bf8_t  __attribute__((ext_vector_type(8)));   // MFMA bf16 frag (4 VGPRs)
typedef unsigned short ub8_t __attribute__((ext_vector_type(8)));

__device__ __forceinline__ unsigned short f2bf(float f) {
    unsigned u = __float_as_uint(f);
    u = (u + 0x7FFFu + ((u >> 16) & 1u)) >> 16;   // RNE
    return (unsigned short)u;
}
__device__ __forceinline__ float bf2f(unsigned short u) {
    return __uint_as_float(((unsigned)u) << 16);
}

// ---------------- zero XpA+XpB (adjacent, 2*2,959,360 us) ----------------
__global__ __launch_bounds__(256) void zero_k(unsigned short* __restrict__ dst) {
    ub8_t zz = {0,0,0,0,0,0,0,0};
    *(ub8_t*)&dst[((size_t)blockIdx.x * 256 + threadIdx.x) * 8] = zz;
}

// ---------------- pad x: fp32 c-major (256,8192) -> interior of XpA[row][256] bf16 ----------------
__global__ __launch_bounds__(256) void pad_x_t(const float* __restrict__ x,
                                               unsigned short* __restrict__ XpA) {
    __shared__ unsigned short T[256 * 33];
    int b = blockIdx.x;
    int z = b >> 5, y = b & 31;
    int t = threadIdx.x;
    int c8 = t >> 5, xv = t & 31;
#pragma unroll 4
    for (int i = 0; i < 32; ++i) {
        int c = i * 8 + c8;
        T[c * 33 + xv] = f2bf(x[c * NPOS + (z << 10) + (y << 5) + xv]);
    }
    __syncthreads();
    int rowb = ((z + 1) * XP_SZ + (y + 1) * XP_SY + 1) * 256;
#pragma unroll 4
    for (int j = 0; j < 32; ++j) {
        XpA[rowb + j * 256 + t] = T[t * 33 + j];
    }
}

// ---------------- all 8 weight transposes in one launch ----------------
// src w[o][c][k] fp32 -> dst[o][k*256+c] bf16
__global__ __launch_bounds__(256) void wtrans_all(
    const float* __restrict__ o1, const float* __restrict__ o2,
    const float* __restrict__ o3, const float* __restrict__ o4,
    const float* __restrict__ m1, const float* __restrict__ m2,
    const float* __restrict__ m3, const float* __restrict__ m4,
    unsigned short* __restrict__ wtoff, unsigned short* __restrict__ wtmain) {
    __shared__ float T[6912];
    int b = blockIdx.x, t = threadIdx.x;
    const float* src; unsigned short* dst; int o, O;
    if (b < 512) {
        int L = b >> 7; o = b & 127; O = 108;
        src = (L == 0) ? o1 : (L == 1) ? o2 : (L == 2) ? o3 : o4;
        dst = wtoff + ((size_t)(L * 128 + o)) * KTOT;
    } else {
        int b2 = b - 512;
        int L = b2 >> 8; o = b2 & 255; O = 256;
        src = (L == 0) ? m1 : (L == 1) ? m2 : (L == 2) ? m3 : m4;
        dst = wtmain + ((size_t)(L * 256 + o)) * KTOT;
    }
    if (o < O) {
#pragma unroll 3
        for (int i = 0; i < 27; ++i) T[i * 256 + t] = src[(size_t)o * KTOT + i * 256 + t];
        __syncthreads();
#pragma unroll 3
        for (int i = 0; i < 27; ++i) {
            int kc = i * 256 + t;
            int c = kc & 255, k = kc >> 8;
            dst[kc] = f2bf(T[c * 27 + k]);
        }
    } else {
#pragma unroll 3
        for (int i = 0; i < 27; ++i) dst[i * 256 + t] = 0;
    }
}

// ---------------- fused implicit GEMM (conv or deformable), K-split partials ----------------
// parts[ks][O][8192] = A[o][kc]*B[p][kc] over kc in [ks*KSL, +KSL)
// Double-buffered B-staging, ONE barrier per chunk. A loaded from global (L2) inside the
// chunk, issued before staging so gather latency covers it. NO cross-chunk register state
// beyond sampling coeffs (R4 post-mortem: cross-chunk A prefetch -> spill disaster).
template<bool DEFORM>
__global__ __launch_bounds__(256, 3)
void fgemm(const unsigned short* __restrict__ Xp,
           const unsigned short* __restrict__ wt,   // [O][KTOT] bf16
           const float* __restrict__ dbuf,          // [108][8192] (DEFORM only)
           float* __restrict__ parts) {
    constexpr int O   = DEFORM ? 256 : 128;
    constexpr int PWN = DEFORM ? 4 : 2;             // p-frags per wave
    constexpr int NCH = KSL / 64;                   // 18
    __shared__ unsigned short Bs[2][64 * 64] __attribute__((aligned(16)));

    const int t = threadIdx.x;
    const int wave = t >> 6, lane = t & 63;
    const int q = lane >> 4, r = lane & 15;
    const int pbase = blockIdx.x * 64;
    const int ks = blockIdx.y;
    const int kstart = ks * KSL;

    const int obw = DEFORM ? (wave * 64) : ((wave >> 1) * 64);
    const int pfb = DEFORM ? 0 : ((wave & 1) * 32);

    // staging coords (R3-exact, 0-conflict): thread -> (p_local = t>>2, 16 ch at csub)
    const int pl = t >> 2;
    const int csub = (t & 3) * 16;
    const int p = pbase + pl;
    const int z = p >> 10, y = (p >> 5) & 31, xx = p & 31;
    const int g0 = (t & 3) * 2;
    const int wr0 = pl * 64 + ((g0 ^ (pl & 7)) << 3);
    const int wr1 = pl * 64 + (((g0 + 1) ^ (pl & 7)) << 3);

    // A row pointers (chunk-invariant)
    const unsigned short* arow[4];
#pragma unroll
    for (int i = 0; i < 4; ++i)
        arow[i] = wt + (size_t)(obw + i * 16 + r) * KTOT + q * 8;

    facc_t acc[4][PWN];
#pragma unroll
    for (int i = 0; i < 4; ++i)
#pragma unroll
        for (int ip = 0; ip < PWN; ++ip) acc[i][ip] = (facc_t){0.f, 0.f, 0.f, 0.f};

    // sampling state (persists across chunks; k monotone)
    float cw[8];
    int row0 = 0;
    int kprev = -1;

    auto stage = [&](int n, int buf) {
        const int kc0 = kstart + n * 64;
        const int k = kc0 >> 8;
        const int c0 = kc0 & 255;
        if (DEFORM) {
            if (k != kprev) {
                kprev = k;
                const int kd = k / 9, kh = (k / 3) % 3, kw = k % 3;
                float od  = dbuf[(3 * k + 0) * NPOS + p];
                float oh  = dbuf[(3 * k + 1) * NPOS + p];
                float ow_ = dbuf[(3 * k + 2) * NPOS + p];
                float m   = dbuf[(81 + k) * NPOS + p];
                float cd = (float)(z + kd - 1) + od;
                float ch = (float)(y + kh - 1) + oh;
                float cx = (float)(xx + kw - 1) + ow_;
                float fdf = floorf(cd), fhf = floorf(ch), fwf = floorf(cx);
                float fd = cd - fdf, fh = ch - fhf, fw = cx - fwf;
                float wz0 = 1.f - fd, wz1 = fd;
                float wy0 = 1.f - fh, wy1 = fh;
                float wx0 = 1.f - fw, wx1 = fw;
                int id, ih, iw;
                if (fdf < -1.f || fdf >= 8.f)  { wz0 = 0.f; wz1 = 0.f; id = 0; } else id = (int)fdf;
                if (fhf < -1.f || fhf >= 32.f) { wy0 = 0.f; wy1 = 0.f; ih = 0; } else ih = (int)fhf;
                if (fwf < -1.f || fwf >= 32.f) { wx0 = 0.f; wx1 = 0.f; iw = 0; } else iw = (int)fwf;
                wz0 *= m; wz1 *= m;
                float w00 = wz0 * wy0, w01 = wz0 * wy1, w10 = wz1 * wy0, w11 = wz1 * wy1;
                cw[0] = w00 * wx0; cw[1] = w00 * wx1;
                cw[2] = w01 * wx0; cw[3] = w01 * wx1;
                cw[4] = w10 * wx0; cw[5] = w10 * wx1;
                cw[6] = w11 * wx0; cw[7] = w11 * wx1;
                row0 = (id + 1) * XP_SZ + (ih + 1) * XP_SY + (iw + 1);
            }
            const unsigned short* cb = Xp + (size_t)row0 * 256 + c0 + csub;
            float av[16];
#pragma unroll
            for (int e = 0; e < 16; ++e) av[e] = 0.f;
#pragma unroll
            for (int j = 0; j < 8; ++j) {
                const int roff = ((j >> 2) & 1) * XP_SZ + ((j >> 1) & 1) * XP_SY + (j & 1);
                ub8_t lo = *(const ub8_t*)(cb + roff * 256);
                ub8_t hi = *(const ub8_t*)(cb + roff * 256 + 8);
#pragma unroll
                for (int e = 0; e < 8; ++e) {
                    av[e]     += cw[j] * bf2f(lo[e]);
                    av[8 + e] += cw[j] * bf2f(hi[e]);
                }
            }
            ub8_t v0, v1;
#pragma unroll
            for (int e = 0; e < 8; ++e) { v0[e] = f2bf(av[e]); v1[e] = f2bf(av[8 + e]); }
            *(ub8_t*)&Bs[buf][wr0] = v0;
            *(ub8_t*)&Bs[buf][wr1] = v1;
        } else {
            const int kd = k / 9, kh = (k / 3) % 3, kw = k % 3;
            int row = (z + kd) * XP_SZ + (y + kh) * XP_SY + (xx + kw);
            ub8_t lo = *(const ub8_t*)&Xp[(size_t)row * 256 + c0 + csub];
            ub8_t hi = *(const ub8_t*)&Xp[(size_t)row * 256 + c0 + csub + 8];
            *(ub8_t*)&Bs[buf][wr0] = lo;
            *(ub8_t*)&Bs[buf][wr1] = hi;
        }
    };

    // chunk body: issue A loads, stage next chunk, MFMA this chunk, one barrier
    auto chunkstep = [&](int n, int buf, bool doStageNext) {
        const int kc0 = kstart + n * 64;
        bf8_t af[2][4];
#pragma unroll
        for (int sl = 0; sl < 2; ++sl)
#pragma unroll
            for (int i = 0; i < 4; ++i)
                af[sl][i] = *(const bf8_t*)(arow[i] + kc0 + sl * 32);
        if (doStageNext) stage(n + 1, buf ^ 1);
#pragma unroll
        for (int sl = 0; sl < 2; ++sl) {
            bf8_t bfr[PWN];
#pragma unroll
            for (int ip = 0; ip < PWN; ++ip) {
                int brow = pfb + ip * 16 + r;
                bfr[ip] = *(const bf8_t*)&Bs[buf][brow * 64 + (((sl * 4 + q) ^ (brow & 7)) << 3)];
            }
#pragma unroll
            for (int i = 0; i < 4; ++i)
#pragma unroll
                for (int ip = 0; ip < PWN; ++ip)
                    acc[i][ip] = __builtin_amdgcn_mfma_f32_16x16x32_bf16(af[sl][i], bfr[ip], acc[i][ip], 0, 0, 0);
        }
        __syncthreads();
    };

    stage(0, 0);
    __syncthreads();
    for (int n = 0; n < NCH; n += 2) {
        chunkstep(n, 0, true);                   // stages n+1 (NCH even -> always valid)
        chunkstep(n + 1, 1, n + 2 < NCH);        // stages n+2
    }

    // ---- epilogue: fp32 partials; C/D map row(o)=q*4+reg, col(p)=r [verified R1-R3] ----
    float* pp = parts + (size_t)ks * O * NPOS;
#pragma unroll
    for (int i = 0; i < 4; ++i)
#pragma unroll
        for (int ip = 0; ip < PWN; ++ip)
#pragma unroll
            for (int reg = 0; reg < 4; ++reg) {
                int o = obw + i * 16 + q * 4 + reg;
                int px = pbase + pfb + ip * 16 + r;
                pp[(size_t)o * NPOS + px] = acc[i][ip][reg];
            }
}

// ---------------- combine conv partials -> dbuf (bias + sigmoid on o>=81) ----------------
__global__ __launch_bounds__(256) void ccombine(const float* __restrict__ parts,
                                                const float* __restrict__ ob,
                                                float* __restrict__ dbuf) {
    int b = blockIdx.x;                 // 108*8
    int o = b >> 3;
    int p4 = ((b & 7) * 256 + threadIdx.x) * 4;
    float s0 = 0, s1 = 0, s2 = 0, s3 = 0;
#pragma unroll
    for (int s = 0; s < KS; ++s) {
        const float4 v = *(const float4*)&parts[((size_t)(s * 128 + o)) * NPOS + p4];
        s0 += v.x; s1 += v.y; s2 += v.z; s3 += v.w;
    }
    float bv = ob[o];
    s0 += bv; s1 += bv; s2 += bv; s3 += bv;
    if (o >= 81) {
        s0 = 1.f / (1.f + __expf(-s0));
        s1 = 1.f / (1.f + __expf(-s1));
        s2 = 1.f / (1.f + __expf(-s2));
        s3 = 1.f / (1.f + __expf(-s3));
    }
    *(float4*)&dbuf[(size_t)o * NPOS + p4] = make_float4(s0, s1, s2, s3);
}

// ---------------- combine deform partials -> relu bf16, transposed into XpB interior ----------------
__global__ __launch_bounds__(256) void dcombine_h(const float* __restrict__ parts,
                                                  const float* __restrict__ bias,
                                                  unsigned short* __restrict__ XpB) {
    __shared__ unsigned short T[64 * 66];
    int p0 = blockIdx.x * 64, o0 = blockIdx.y * 64;
    int t = threadIdx.x;
    int pl = t & 63, og = t >> 6;
#pragma unroll 4
    for (int j = 0; j < 16; ++j) {
        int ol = og * 16 + j;
        float s = 0.f;
#pragma unroll
        for (int sp = 0; sp < KS; ++sp)
            s += parts[((size_t)(sp * 256 + o0 + ol)) * NPOS + p0 + pl];
        s += bias[o0 + ol];
        T[ol * 66 + pl] = f2bf(fmaxf(s, 0.f));
    }
    __syncthreads();
    int c = t & 63, pr = t >> 6;
#pragma unroll 4
    for (int j = 0; j < 16; ++j) {
        int pl2 = j * 4 + pr;
        int pg = p0 + pl2;
        int zz = pg >> 10, yy = (pg >> 5) & 31, xv = pg & 31;
        int row = (zz + 1) * XP_SZ + (yy + 1) * XP_SY + xv + 1;
        XpB[(size_t)row * 256 + o0 + c] = T[c * 66 + pl2];
    }
}

// ---------------- final combine -> fp32 o-major output (bias only) ----------------
__global__ __launch_bounds__(256) void dcombine_out(const float* __restrict__ parts,
                                                    const float* __restrict__ bias,
                                                    float* __restrict__ out) {
    int b = blockIdx.x;                 // 256*8
    int o = b >> 3;
    int p4 = ((b & 7) * 256 + threadIdx.x) * 4;
    float s0 = 0, s1 = 0, s2 = 0, s3 = 0;
#pragma unroll
    for (int s = 0; s < KS; ++s) {
        const float4 v = *(const float4*)&parts[((size_t)(s * 256 + o)) * NPOS + p4];
        s0 += v.x; s1 += v.y; s2 += v.z; s3 += v.w;
    }
    float bv = bias[o];
    *(float4*)&out[(size_t)o * NPOS + p4] = make_float4(s0 + bv, s1 + bv, s2 + bv, s3 + bv);
}

// ---------------- host orchestration ----------------
extern "C" void kernel_launch(void* const* d_in, const int* in_sizes, int n_in,
                              void* d_out, int out_size, void* d_ws, size_t ws_size,
                              hipStream_t stream) {
    const float* x      = (const float*)d_in[0];
    const float* ow1    = (const float*)d_in[1];
    const float* ob1    = (const float*)d_in[2];
    const float* w1     = (const float*)d_in[3];
    const float* b1     = (const float*)d_in[4];
    const float* ow2    = (const float*)d_in[5];
    const float* ob2    = (const float*)d_in[6];
    const float* w2     = (const float*)d_in[7];
    const float* b2     = (const float*)d_in[8];
    const float* ow3    = (const float*)d_in[9];
    const float* ob3    = (const float*)d_in[10];
    const float* w3     = (const float*)d_in[11];
    const float* b3     = (const float*)d_in[12];
    const float* defo_w = (const float*)d_in[13];
    const float* defo_b = (const float*)d_in[14];
    const float* c3d_w  = (const float*)d_in[15];
    const float* c3d_b  = (const float*)d_in[16];
    float* out = (float*)d_out;

    // workspace carve-up (~70 MB)
    unsigned short* XpA    = (unsigned short*)d_ws;          // 2,959,360 us
    unsigned short* XpB    = XpA + (size_t)XP_ROWS * 256;    // 2,959,360 us (adjacent for zero_k)
    unsigned short* wtoff  = XpB + (size_t)XP_ROWS * 256;    // 4*128*6912 us
    unsigned short* wtmain = wtoff + (size_t)4 * 128 * KTOT; // 4*256*6912 us
    float* dbufp = (float*)(wtmain + (size_t)4 * 256 * KTOT);// 108*8192 fp32
    float* parts = dbufp + (size_t)108 * NPOS;               // KS*256*8192 fp32 = 50.3 MB

    const dim3 blk(256);
    const dim3 gG(128, KS);

    zero_k<<<2890, blk, 0, stream>>>(XpA);                   // zeros XpA + XpB
    pad_x_t<<<256, blk, 0, stream>>>(x, XpA);
    wtrans_all<<<1536, blk, 0, stream>>>(ow1, ow2, ow3, defo_w, w1, w2, w3, c3d_w, wtoff, wtmain);

    const float* cbias[4] = {ob1, ob2, ob3, defo_b};
    const float* dbias[4] = {b1, b2, b3, c3d_b};

    for (int L = 0; L < 4; ++L) {
        const unsigned short* featConv = (L == 0) ? XpA : XpB;          // conv input = h_{L-1}
        const unsigned short* featDef  = (L == 3) ? XpA : featConv;     // final deform samples original x
        fgemm<false><<<gG, blk, 0, stream>>>(featConv, wtoff + (size_t)L * 128 * KTOT, nullptr, parts);
        ccombine<<<864, blk, 0, stream>>>(parts, cbias[L], dbufp);
        fgemm<true><<<gG, blk, 0, stream>>>(featDef, wtmain + (size_t)L * 256 * KTOT, dbufp, parts);
        if (L < 3) dcombine_h<<<dim3(128, 4), blk, 0, stream>>>(parts, dbias[L], XpB);
        else       dcombine_out<<<2048, blk, 0, stream>>>(parts, dbias[L], out);
    }
}

// Round 6
// 865.460 us; speedup vs baseline: 1.9765x; 1.9765x over previous
//
#include <hip/hip_runtime.h>
#include <cstdint>

// ---------------- problem constants ----------------
#define NPOS 8192              // 8*32*32 spatial positions
#define KTOT 6912              // 27 taps * 256 channels
#define XP_ROWS 11560          // 10*34*34 padded spatial rows
#define XP_SY 34
#define XP_SZ 1156             // 34*34
#define KS 6                   // K-splits
#define KSL 1152               // KTOT/KS (18 chunks of 64)

typedef float  facc_t __attribute__((ext_vector_type(4)));
typedef short  bf8_t  __attribute__((ext_vector_type(8)));   // MFMA bf16 frag (4 VGPRs)
typedef unsigned short ub8_t __attribute__((ext_vector_type(8)));

__device__ __forceinline__ unsigned short f2bf(float f) {
    unsigned u = __float_as_uint(f);
    u = (u + 0x7FFFu + ((u >> 16) & 1u)) >> 16;   // RNE
    return (unsigned short)u;
}
__device__ __forceinline__ float bf2f(unsigned short u) {
    return __uint_as_float(((unsigned)u) << 16);
}

// ---------------- zero XpA+XpB (adjacent, 2*2,959,360 us) ----------------
__global__ __launch_bounds__(256) void zero_k(unsigned short* __restrict__ dst) {
    ub8_t zz = {0,0,0,0,0,0,0,0};
    *(ub8_t*)&dst[((size_t)blockIdx.x * 256 + threadIdx.x) * 8] = zz;
}

// ---------------- pad x: fp32 c-major (256,8192) -> interior of XpA[row][256] bf16 ----------------
__global__ __launch_bounds__(256) void pad_x_t(const float* __restrict__ x,
                                               unsigned short* __restrict__ XpA) {
    __shared__ unsigned short T[256 * 33];
    int b = blockIdx.x;
    int z = b >> 5, y = b & 31;
    int t = threadIdx.x;
    int c8 = t >> 5, xv = t & 31;
#pragma unroll 4
    for (int i = 0; i < 32; ++i) {
        int c = i * 8 + c8;
        T[c * 33 + xv] = f2bf(x[c * NPOS + (z << 10) + (y << 5) + xv]);
    }
    __syncthreads();
    int rowb = ((z + 1) * XP_SZ + (y + 1) * XP_SY + 1) * 256;
#pragma unroll 4
    for (int j = 0; j < 32; ++j) {
        XpA[rowb + j * 256 + t] = T[t * 33 + j];
    }
}

// ---------------- all 8 weight transposes in one launch ----------------
// src w[o][c][k] fp32 -> dst[o][k*256+c] bf16
__global__ __launch_bounds__(256) void wtrans_all(
    const float* __restrict__ o1, const float* __restrict__ o2,
    const float* __restrict__ o3, const float* __restrict__ o4,
    const float* __restrict__ m1, const float* __restrict__ m2,
    const float* __restrict__ m3, const float* __restrict__ m4,
    unsigned short* __restrict__ wtoff, unsigned short* __restrict__ wtmain) {
    __shared__ float T[6912];
    int b = blockIdx.x, t = threadIdx.x;
    const float* src; unsigned short* dst; int o, O;
    if (b < 512) {
        int L = b >> 7; o = b & 127; O = 108;
        src = (L == 0) ? o1 : (L == 1) ? o2 : (L == 2) ? o3 : o4;
        dst = wtoff + ((size_t)(L * 128 + o)) * KTOT;
    } else {
        int b2 = b - 512;
        int L = b2 >> 8; o = b2 & 255; O = 256;
        src = (L == 0) ? m1 : (L == 1) ? m2 : (L == 2) ? m3 : m4;
        dst = wtmain + ((size_t)(L * 256 + o)) * KTOT;
    }
    if (o < O) {
#pragma unroll 3
        for (int i = 0; i < 27; ++i) T[i * 256 + t] = src[(size_t)o * KTOT + i * 256 + t];
        __syncthreads();
#pragma unroll 3
        for (int i = 0; i < 27; ++i) {
            int kc = i * 256 + t;
            int c = kc & 255, k = kc >> 8;
            dst[kc] = f2bf(T[c * 27 + k]);
        }
    } else {
#pragma unroll 3
        for (int i = 0; i < 27; ++i) dst[i * 256 + t] = 0;
    }
}

// ---------------- fused implicit GEMM (conv or deformable), K-split partials ----------------
// R3-exact structure (stage -> barrier -> A-load+MFMA -> barrier): keeps staging temps and
// MFMA fragments in DISJOINT live ranges. R4/R5 post-mortem: any overlap of A-frags with the
// gather loop lets the scheduler hold 16 in-flight gathers on top of acc[64] -> scratch spill.
template<bool DEFORM>
__global__ __launch_bounds__(256)
void fgemm(const unsigned short* __restrict__ Xp,
           const unsigned short* __restrict__ wt,   // [O][KTOT] bf16
           const float* __restrict__ dbuf,          // [108][8192] (DEFORM only)
           float* __restrict__ parts) {
    constexpr int O   = DEFORM ? 256 : 128;
    constexpr int PWN = DEFORM ? 4 : 2;             // p-frags per wave
    __shared__ unsigned short Bs[64 * 64] __attribute__((aligned(16)));

    const int t = threadIdx.x;
    const int wave = t >> 6, lane = t & 63;
    const int q = lane >> 4, r = lane & 15;
    const int pbase = blockIdx.x * 64;
    const int ks = blockIdx.y;
    const int kstart = ks * KSL;

    const int obw = DEFORM ? (wave * 64) : ((wave >> 1) * 64);
    const int pfb = DEFORM ? 0 : ((wave & 1) * 32);

    // staging coords: thread -> (p_local = t>>2, 16 channels at csub)
    const int pl = t >> 2;
    const int csub = (t & 3) * 16;
    const int p = pbase + pl;
    const int z = p >> 10, y = (p >> 5) & 31, xx = p & 31;
    const int g0 = (t & 3) * 2;
    const int wr0 = pl * 64 + ((g0 ^ (pl & 7)) << 3);
    const int wr1 = pl * 64 + (((g0 + 1) ^ (pl & 7)) << 3);

    facc_t acc[4][PWN];
#pragma unroll
    for (int i = 0; i < 4; ++i)
#pragma unroll
        for (int ip = 0; ip < PWN; ++ip) acc[i][ip] = (facc_t){0.f, 0.f, 0.f, 0.f};

    float cw[8];
    int row0 = 0;
    int kprev = -1;

    for (int chunk = 0; chunk < KSL / 64; ++chunk) {
        const int kc0 = kstart + chunk * 64;
        const int k = kc0 >> 8;
        const int c0 = kc0 & 255;
        const int kd = k / 9, kh = (k / 3) % 3, kw = k % 3;

        // ---- A-fragments straight from global (L2-resident weights) ----
        bf8_t afr[2][4];
#pragma unroll
        for (int sl = 0; sl < 2; ++sl)
#pragma unroll
            for (int i = 0; i < 4; ++i)
                afr[sl][i] = *(const bf8_t*)&wt[(size_t)(obw + i * 16 + r) * KTOT + kc0 + sl * 32 + q * 8];

        // ---- B staging ----
        if (DEFORM) {
            if (k != kprev) {
                kprev = k;
                float od  = dbuf[(3 * k + 0) * NPOS + p];
                float oh  = dbuf[(3 * k + 1) * NPOS + p];
                float ow_ = dbuf[(3 * k + 2) * NPOS + p];
                float m   = dbuf[(81 + k) * NPOS + p];
                float cd = (float)(z + kd - 1) + od;
                float ch = (float)(y + kh - 1) + oh;
                float cx = (float)(xx + kw - 1) + ow_;
                float fdf = floorf(cd), fhf = floorf(ch), fwf = floorf(cx);
                float fd = cd - fdf, fh = ch - fhf, fw = cx - fwf;
                float wz0 = 1.f - fd, wz1 = fd;
                float wy0 = 1.f - fh, wy1 = fh;
                float wx0 = 1.f - fw, wx1 = fw;
                int id, ih, iw;
                if (fdf < -1.f || fdf >= 8.f)  { wz0 = 0.f; wz1 = 0.f; id = 0; } else id = (int)fdf;
                if (fhf < -1.f || fhf >= 32.f) { wy0 = 0.f; wy1 = 0.f; ih = 0; } else ih = (int)fhf;
                if (fwf < -1.f || fwf >= 32.f) { wx0 = 0.f; wx1 = 0.f; iw = 0; } else iw = (int)fwf;
                wz0 *= m; wz1 *= m;
                float w00 = wz0 * wy0, w01 = wz0 * wy1, w10 = wz1 * wy0, w11 = wz1 * wy1;
                cw[0] = w00 * wx0; cw[1] = w00 * wx1;
                cw[2] = w01 * wx0; cw[3] = w01 * wx1;
                cw[4] = w10 * wx0; cw[5] = w10 * wx1;
                cw[6] = w11 * wx0; cw[7] = w11 * wx1;
                row0 = (id + 1) * XP_SZ + (ih + 1) * XP_SY + (iw + 1);
            }
            float av[16];
#pragma unroll
            for (int e = 0; e < 16; ++e) av[e] = 0.f;
            const unsigned short* cb = Xp + (size_t)row0 * 256 + c0 + csub;
#pragma unroll
            for (int j = 0; j < 8; ++j) {
                const int roff = ((j >> 2) & 1) * XP_SZ + ((j >> 1) & 1) * XP_SY + (j & 1);
                ub8_t lo = *(const ub8_t*)(cb + roff * 256);
                ub8_t hi = *(const ub8_t*)(cb + roff * 256 + 8);
#pragma unroll
                for (int e = 0; e < 8; ++e) {
                    av[e]     += cw[j] * bf2f(lo[e]);
                    av[8 + e] += cw[j] * bf2f(hi[e]);
                }
            }
            ub8_t v0, v1;
#pragma unroll
            for (int e = 0; e < 8; ++e) { v0[e] = f2bf(av[e]); v1[e] = f2bf(av[8 + e]); }
            *(ub8_t*)&Bs[wr0] = v0;
            *(ub8_t*)&Bs[wr1] = v1;
        } else {
            int row = (z + kd) * XP_SZ + (y + kh) * XP_SY + (xx + kw);
            ub8_t lo = *(const ub8_t*)&Xp[(size_t)row * 256 + c0 + csub];
            ub8_t hi = *(const ub8_t*)&Xp[(size_t)row * 256 + c0 + csub + 8];
            *(ub8_t*)&Bs[wr0] = lo;
            *(ub8_t*)&Bs[wr1] = hi;
        }
        __syncthreads();

        // ---- MFMA ----
#pragma unroll
        for (int sl = 0; sl < 2; ++sl) {
            bf8_t bfr[PWN];
#pragma unroll
            for (int ip = 0; ip < PWN; ++ip) {
                int brow = pfb + ip * 16 + r;
                bfr[ip] = *(const bf8_t*)&Bs[brow * 64 + (((sl * 4 + q) ^ (brow & 7)) << 3)];
            }
#pragma unroll
            for (int i = 0; i < 4; ++i)
#pragma unroll
                for (int ip = 0; ip < PWN; ++ip)
                    acc[i][ip] = __builtin_amdgcn_mfma_f32_16x16x32_bf16(afr[sl][i], bfr[ip], acc[i][ip], 0, 0, 0);
        }
        __syncthreads();
    }

    // ---- epilogue: fp32 partials; C/D map row(o)=q*4+reg, col(p)=r [verified R1-R3] ----
    float* pp = parts + (size_t)ks * O * NPOS;
#pragma unroll
    for (int i = 0; i < 4; ++i)
#pragma unroll
        for (int ip = 0; ip < PWN; ++ip)
#pragma unroll
            for (int reg = 0; reg < 4; ++reg) {
                int o = obw + i * 16 + q * 4 + reg;
                int px = pbase + pfb + ip * 16 + r;
                pp[(size_t)o * NPOS + px] = acc[i][ip][reg];
            }
}

// ---------------- combine conv partials -> dbuf (bias + sigmoid on o>=81) ----------------
__global__ __launch_bounds__(256) void ccombine(const float* __restrict__ parts,
                                                const float* __restrict__ ob,
                                                float* __restrict__ dbuf) {
    int b = blockIdx.x;                 // 108*8
    int o = b >> 3;
    int p4 = ((b & 7) * 256 + threadIdx.x) * 4;
    float s0 = 0, s1 = 0, s2 = 0, s3 = 0;
#pragma unroll
    for (int s = 0; s < KS; ++s) {
        const float4 v = *(const float4*)&parts[((size_t)(s * 128 + o)) * NPOS + p4];
        s0 += v.x; s1 += v.y; s2 += v.z; s3 += v.w;
    }
    float bv = ob[o];
    s0 += bv; s1 += bv; s2 += bv; s3 += bv;
    if (o >= 81) {
        s0 = 1.f / (1.f + __expf(-s0));
        s1 = 1.f / (1.f + __expf(-s1));
        s2 = 1.f / (1.f + __expf(-s2));
        s3 = 1.f / (1.f + __expf(-s3));
    }
    *(float4*)&dbuf[(size_t)o * NPOS + p4] = make_float4(s0, s1, s2, s3);
}

// ---------------- combine deform partials -> relu bf16, transposed into XpB interior ----------------
__global__ __launch_bounds__(256) void dcombine_h(const float* __restrict__ parts,
                                                  const float* __restrict__ bias,
                                                  unsigned short* __restrict__ XpB) {
    __shared__ unsigned short T[64 * 66];
    int p0 = blockIdx.x * 64, o0 = blockIdx.y * 64;
    int t = threadIdx.x;
    int pl = t & 63, og = t >> 6;
#pragma unroll 4
    for (int j = 0; j < 16; ++j) {
        int ol = og * 16 + j;
        float s = 0.f;
#pragma unroll
        for (int sp = 0; sp < KS; ++sp)
            s += parts[((size_t)(sp * 256 + o0 + ol)) * NPOS + p0 + pl];
        s += bias[o0 + ol];
        T[ol * 66 + pl] = f2bf(fmaxf(s, 0.f));
    }
    __syncthreads();
    int c = t & 63, pr = t >> 6;
#pragma unroll 4
    for (int j = 0; j < 16; ++j) {
        int pl2 = j * 4 + pr;
        int pg = p0 + pl2;
        int zz = pg >> 10, yy = (pg >> 5) & 31, xv = pg & 31;
        int row = (zz + 1) * XP_SZ + (yy + 1) * XP_SY + xv + 1;
        XpB[(size_t)row * 256 + o0 + c] = T[c * 66 + pl2];
    }
}

// ---------------- final combine -> fp32 o-major output (bias only) ----------------
__global__ __launch_bounds__(256) void dcombine_out(const float* __restrict__ parts,
                                                    const float* __restrict__ bias,
                                                    float* __restrict__ out) {
    int b = blockIdx.x;                 // 256*8
    int o = b >> 3;
    int p4 = ((b & 7) * 256 + threadIdx.x) * 4;
    float s0 = 0, s1 = 0, s2 = 0, s3 = 0;
#pragma unroll
    for (int s = 0; s < KS; ++s) {
        const float4 v = *(const float4*)&parts[((size_t)(s * 256 + o)) * NPOS + p4];
        s0 += v.x; s1 += v.y; s2 += v.z; s3 += v.w;
    }
    float bv = bias[o];
    *(float4*)&out[(size_t)o * NPOS + p4] = make_float4(s0 + bv, s1 + bv, s2 + bv, s3 + bv);
}

// ---------------- host orchestration ----------------
extern "C" void kernel_launch(void* const* d_in, const int* in_sizes, int n_in,
                              void* d_out, int out_size, void* d_ws, size_t ws_size,
                              hipStream_t stream) {
    const float* x      = (const float*)d_in[0];
    const float* ow1    = (const float*)d_in[1];
    const float* ob1    = (const float*)d_in[2];
    const float* w1     = (const float*)d_in[3];
    const float* b1     = (const float*)d_in[4];
    const float* ow2    = (const float*)d_in[5];
    const float* ob2    = (const float*)d_in[6];
    const float* w2     = (const float*)d_in[7];
    const float* b2     = (const float*)d_in[8];
    const float* ow3    = (const float*)d_in[9];
    const float* ob3    = (const float*)d_in[10];
    const float* w3     = (const float*)d_in[11];
    const float* b3     = (const float*)d_in[12];
    const float* defo_w = (const float*)d_in[13];
    const float* defo_b = (const float*)d_in[14];
    const float* c3d_w  = (const float*)d_in[15];
    const float* c3d_b  = (const float*)d_in[16];
    float* out = (float*)d_out;

    // workspace carve-up (~70 MB)
    unsigned short* XpA    = (unsigned short*)d_ws;          // 2,959,360 us
    unsigned short* XpB    = XpA + (size_t)XP_ROWS * 256;    // 2,959,360 us (adjacent for zero_k)
    unsigned short* wtoff  = XpB + (size_t)XP_ROWS * 256;    // 4*128*6912 us
    unsigned short* wtmain = wtoff + (size_t)4 * 128 * KTOT; // 4*256*6912 us
    float* dbufp = (float*)(wtmain + (size_t)4 * 256 * KTOT);// 108*8192 fp32
    float* parts = dbufp + (size_t)108 * NPOS;               // KS*256*8192 fp32 = 50.3 MB

    const dim3 blk(256);
    const dim3 gG(128, KS);

    zero_k<<<2890, blk, 0, stream>>>(XpA);                   // zeros XpA + XpB
    pad_x_t<<<256, blk, 0, stream>>>(x, XpA);
    wtrans_all<<<1536, blk, 0, stream>>>(ow1, ow2, ow3, defo_w, w1, w2, w3, c3d_w, wtoff, wtmain);

    const float* cbias[4] = {ob1, ob2, ob3, defo_b};
    const float* dbias[4] = {b1, b2, b3, c3d_b};

    for (int L = 0; L < 4; ++L) {
        const unsigned short* featConv = (L == 0) ? XpA : XpB;          // conv input = h_{L-1}
        const unsigned short* featDef  = (L == 3) ? XpA : featConv;     // final deform samples original x
        fgemm<false><<<gG, blk, 0, stream>>>(featConv, wtoff + (size_t)L * 128 * KTOT, nullptr, parts);
        ccombine<<<864, blk, 0, stream>>>(parts, cbias[L], dbufp);
        fgemm<true><<<gG, blk, 0, stream>>>(featDef, wtmain + (size_t)L * 256 * KTOT, dbufp, parts);
        if (L < 3) dcombine_h<<<dim3(128, 4), blk, 0, stream>>>(parts, dbias[L], XpB);
        else       dcombine_out<<<2048, blk, 0, stream>>>(parts, dbias[L], out);
    }
}

// Round 7
// 862.108 us; speedup vs baseline: 1.9842x; 1.0039x over previous
//
#include <hip/hip_runtime.h>
#include <cstdint>

// ---------------- problem constants ----------------
#define NPOS 8192              // 8*32*32 spatial positions
#define KTOT 6912              // 27 taps * 256 channels
#define XP_ROWS 11560          // 10*34*34 padded spatial rows
#define XP_SY 34
#define XP_SZ 1156             // 34*34
#define KS 8                   // K-splits
#define KSL 864                // KTOT/KS (27 chunks of 32)

typedef float  facc_t __attribute__((ext_vector_type(4)));
typedef short  bf8_t  __attribute__((ext_vector_type(8)));   // MFMA bf16 frag (4 VGPRs)
typedef unsigned short ub8_t __attribute__((ext_vector_type(8)));
typedef float  f4_t   __attribute__((ext_vector_type(4)));

__device__ __forceinline__ unsigned short f2bf(float f) {
    unsigned u = __float_as_uint(f);
    u = (u + 0x7FFFu + ((u >> 16) & 1u)) >> 16;   // RNE
    return (unsigned short)u;
}
__device__ __forceinline__ float bf2f(unsigned short u) {
    return __uint_as_float(((unsigned)u) << 16);
}

// async global->LDS, 16B/lane, LDS dest = wave-uniform base + lane*16 (no dest VGPRs!)
__device__ __forceinline__ void gl_lds16(const unsigned short* g, unsigned short* l) {
    __builtin_amdgcn_global_load_lds(
        (const __attribute__((address_space(1))) unsigned int*)g,
        (__attribute__((address_space(3))) unsigned int*)l, 16, 0, 0);
}

// ---------------- zero XpA+XpB (adjacent, 2*2,959,360 us) ----------------
__global__ __launch_bounds__(256) void zero_k(unsigned short* __restrict__ dst) {
    ub8_t zz = {0,0,0,0,0,0,0,0};
    *(ub8_t*)&dst[((size_t)blockIdx.x * 256 + threadIdx.x) * 8] = zz;
}

// ---------------- pad x: fp32 c-major (256,8192) -> interior of XpA[row][256] bf16 ----------------
__global__ __launch_bounds__(256) void pad_x_t(const float* __restrict__ x,
                                               unsigned short* __restrict__ XpA) {
    __shared__ unsigned short T[256 * 33];
    int b = blockIdx.x;
    int z = b >> 5, y = b & 31;
    int t = threadIdx.x;
    int c8 = t >> 5, xv = t & 31;
#pragma unroll 4
    for (int i = 0; i < 32; ++i) {
        int c = i * 8 + c8;
        T[c * 33 + xv] = f2bf(x[c * NPOS + (z << 10) + (y << 5) + xv]);
    }
    __syncthreads();
    int rowb = ((z + 1) * XP_SZ + (y + 1) * XP_SY + 1) * 256;
#pragma unroll 4
    for (int j = 0; j < 32; ++j) {
        XpA[rowb + j * 256 + t] = T[t * 33 + j];
    }
}

// ---------------- all 8 weight transposes in one launch ----------------
__global__ __launch_bounds__(256) void wtrans_all(
    const float* __restrict__ o1, const float* __restrict__ o2,
    const float* __restrict__ o3, const float* __restrict__ o4,
    const float* __restrict__ m1, const float* __restrict__ m2,
    const float* __restrict__ m3, const float* __restrict__ m4,
    unsigned short* __restrict__ wtoff, unsigned short* __restrict__ wtmain) {
    __shared__ float T[6912];
    int b = blockIdx.x, t = threadIdx.x;
    const float* src; unsigned short* dst; int o, O;
    if (b < 512) {
        int L = b >> 7; o = b & 127; O = 108;
        src = (L == 0) ? o1 : (L == 1) ? o2 : (L == 2) ? o3 : o4;
        dst = wtoff + ((size_t)(L * 128 + o)) * KTOT;
    } else {
        int b2 = b - 512;
        int L = b2 >> 8; o = b2 & 255; O = 256;
        src = (L == 0) ? m1 : (L == 1) ? m2 : (L == 2) ? m3 : m4;
        dst = wtmain + ((size_t)(L * 256 + o)) * KTOT;
    }
    if (o < O) {
#pragma unroll 3
        for (int i = 0; i < 27; ++i) T[i * 256 + t] = src[(size_t)o * KTOT + i * 256 + t];
        __syncthreads();
#pragma unroll 3
        for (int i = 0; i < 27; ++i) {
            int kc = i * 256 + t;
            int c = kc & 255, k = kc >> 8;
            dst[kc] = f2bf(T[c * 27 + k]);
        }
    } else {
#pragma unroll 3
        for (int i = 0; i < 27; ++i) dst[i * 256 + t] = 0;
    }
}

// ---------------- fused implicit GEMM, BK=32, K-split partials ----------------
// DEFORM staging: tap tables (rowtab/cwtab) in LDS -> 8 async corner global_load_lds
// per thread (NO dest registers -> all in flight, one drain) -> LDS combine -> Bs -> MFMA.
// Phases barrier-disjoint (R4/R5 rule: no staging temps live across MFMA).
template<bool DEFORM>
__global__ __launch_bounds__(256, 4)
void fgemm(const unsigned short* __restrict__ Xp,
           const unsigned short* __restrict__ wt,   // [O][KTOT] bf16
           const float* __restrict__ dbuf,          // [108][8192] (DEFORM only)
           float* __restrict__ parts) {
    constexpr int O   = DEFORM ? 256 : 128;
    constexpr int PWN = DEFORM ? 4 : 2;             // p-frags per wave
    constexpr int NCH = KSL / 32;                   // 27
    // LDS: Cbuf[p][j][quad] 16B slots (32 KB), Bs 4 KB, tap tables
    __shared__ unsigned short Cbuf[DEFORM ? 16384 : 1] __attribute__((aligned(16)));
    __shared__ unsigned short Bs[64 * 32] __attribute__((aligned(16)));
    __shared__ int   rowtab_s[DEFORM ? 64 : 1];
    __shared__ float cwtab_s[DEFORM ? 512 : 1];

    const int t = threadIdx.x;
    const int wave = t >> 6, lane = t & 63;
    const int q = lane >> 4, r = lane & 15;
    const int pbase = blockIdx.x * 64;
    const int ks = blockIdx.y;
    const int kstart = ks * KSL;

    const int obw = DEFORM ? (wave * 64) : ((wave >> 1) * 64);
    const int pfb = DEFORM ? 0 : ((wave & 1) * 32);

    // combine/conv-staging coords
    const int pl = t >> 2;
    const int cg = t & 3;
    const int p = pbase + pl;
    const int z = p >> 10, y = (p >> 5) & 31, xx = p & 31;
    const int bswr = pl * 32 + ((cg ^ (pl & 3)) << 3);   // Bs write slot (shorts)

    // deform staging coords (fixed per thread): qid = i*256+t -> p=i*8+(t>>5), j=(t>>2)&7, quad=t&3
    const int sj   = (t >> 2) & 7;
    const int squad = t & 3;
    const int sroff = ((sj >> 2) & 1) * XP_SZ + ((sj >> 1) & 1) * XP_SY + (sj & 1);
    const int sphi = t >> 5;

    facc_t acc[4][PWN];
#pragma unroll
    for (int i = 0; i < 4; ++i)
#pragma unroll
        for (int ip = 0; ip < PWN; ++ip) acc[i][ip] = (facc_t){0.f, 0.f, 0.f, 0.f};

    for (int chunk = 0; chunk < NCH; ++chunk) {
        const int kc0 = kstart + chunk * 32;
        const int k = kc0 >> 8;
        const int c0 = kc0 & 255;

        if (DEFORM) {
            // ---- tap setup (once per tap): rowtab + cwtab into LDS ----
            if (chunk == 0 || c0 == 0) {
                if (t < 64) {
                    const int kd = k / 9, kh = (k / 3) % 3, kw = k % 3;
                    int pp = pbase + t;
                    int zz2 = pp >> 10, yy2 = (pp >> 5) & 31, xx2 = pp & 31;
                    float od  = dbuf[(3 * k + 0) * NPOS + pp];
                    float oh  = dbuf[(3 * k + 1) * NPOS + pp];
                    float ow_ = dbuf[(3 * k + 2) * NPOS + pp];
                    float m   = dbuf[(81 + k) * NPOS + pp];
                    float cd = (float)(zz2 + kd - 1) + od;
                    float ch = (float)(yy2 + kh - 1) + oh;
                    float cx = (float)(xx2 + kw - 1) + ow_;
                    float fdf = floorf(cd), fhf = floorf(ch), fwf = floorf(cx);
                    float fd = cd - fdf, fh = ch - fhf, fw = cx - fwf;
                    float wz0 = 1.f - fd, wz1 = fd;
                    float wy0 = 1.f - fh, wy1 = fh;
                    float wx0 = 1.f - fw, wx1 = fw;
                    int id, ih, iw;
                    if (fdf < -1.f || fdf >= 8.f)  { wz0 = 0.f; wz1 = 0.f; id = 0; } else id = (int)fdf;
                    if (fhf < -1.f || fhf >= 32.f) { wy0 = 0.f; wy1 = 0.f; ih = 0; } else ih = (int)fhf;
                    if (fwf < -1.f || fwf >= 32.f) { wx0 = 0.f; wx1 = 0.f; iw = 0; } else iw = (int)fwf;
                    wz0 *= m; wz1 *= m;
                    float w00 = wz0 * wy0, w01 = wz0 * wy1, w10 = wz1 * wy0, w11 = wz1 * wy1;
                    rowtab_s[t] = (id + 1) * XP_SZ + (ih + 1) * XP_SY + (iw + 1);
                    cwtab_s[t * 8 + 0] = w00 * wx0; cwtab_s[t * 8 + 1] = w00 * wx1;
                    cwtab_s[t * 8 + 2] = w01 * wx0; cwtab_s[t * 8 + 3] = w01 * wx1;
                    cwtab_s[t * 8 + 4] = w10 * wx0; cwtab_s[t * 8 + 5] = w10 * wx1;
                    cwtab_s[t * 8 + 6] = w11 * wx0; cwtab_s[t * 8 + 7] = w11 * wx1;
                }
                __syncthreads();
            }
            // ---- async corner staging: 8 global_load_lds, no dest regs ----
#pragma unroll
            for (int i = 0; i < 8; ++i) {
                int plo = i * 8 + sphi;
                int row = rowtab_s[plo] + sroff;
                gl_lds16(Xp + (size_t)row * 256 + c0 + squad * 8,
                         &Cbuf[(i * 256 + (t & ~63)) * 8]);
            }
            __syncthreads();   // drains vmcnt (compiler inserts)
            // ---- combine: weighted sum of 8 corners -> Bs ----
            {
                f4_t cw0 = *(const f4_t*)&cwtab_s[pl * 8];
                f4_t cw1 = *(const f4_t*)&cwtab_s[pl * 8 + 4];
                float av[8];
#pragma unroll
                for (int e = 0; e < 8; ++e) av[e] = 0.f;
#pragma unroll
                for (int j = 0; j < 8; ++j) {
                    ub8_t v = *(const ub8_t*)&Cbuf[pl * 256 + j * 32 + cg * 8];
                    float w = (j < 4) ? cw0[j] : cw1[j - 4];
#pragma unroll
                    for (int e = 0; e < 8; ++e) av[e] += w * bf2f(v[e]);
                }
                ub8_t pk;
#pragma unroll
                for (int e = 0; e < 8; ++e) pk[e] = f2bf(av[e]);
                *(ub8_t*)&Bs[bswr] = pk;
            }
        } else {
            // ---- conv staging: direct row copy ----
            const int kd = k / 9, kh = (k / 3) % 3, kw = k % 3;
            int row = (z + kd) * XP_SZ + (y + kh) * XP_SY + (xx + kw);
            ub8_t v = *(const ub8_t*)&Xp[(size_t)row * 256 + c0 + cg * 8];
            *(ub8_t*)&Bs[bswr] = v;
        }
        __syncthreads();

        // ---- MFMA: A-frags from global (L2-resident), B from Bs ----
#pragma unroll
        for (int i = 0; i < 4; ++i) {
            bf8_t a = *(const bf8_t*)&wt[(size_t)(obw + i * 16 + r) * KTOT + kc0 + q * 8];
#pragma unroll
            for (int ip = 0; ip < PWN; ++ip) {
                int brow = pfb + ip * 16 + r;
                bf8_t b = *(const bf8_t*)&Bs[brow * 32 + ((q ^ (brow & 3)) << 3)];
                acc[i][ip] = __builtin_amdgcn_mfma_f32_16x16x32_bf16(a, b, acc[i][ip], 0, 0, 0);
            }
        }
        __syncthreads();
    }

    // ---- epilogue: fp32 partials; C/D map row(o)=q*4+reg, col(p)=r [verified R1-R6] ----
    float* pp = parts + (size_t)ks * O * NPOS;
#pragma unroll
    for (int i = 0; i < 4; ++i)
#pragma unroll
        for (int ip = 0; ip < PWN; ++ip)
#pragma unroll
            for (int reg = 0; reg < 4; ++reg) {
                int o = obw + i * 16 + q * 4 + reg;
                int px = pbase + pfb + ip * 16 + r;
                pp[(size_t)o * NPOS + px] = acc[i][ip][reg];
            }
}

// ---------------- combine conv partials -> dbuf (bias + sigmoid on o>=81) ----------------
__global__ __launch_bounds__(256) void ccombine(const float* __restrict__ parts,
                                                const float* __restrict__ ob,
                                                float* __restrict__ dbuf) {
    int b = blockIdx.x;                 // 108*8
    int o = b >> 3;
    int p4 = ((b & 7) * 256 + threadIdx.x) * 4;
    float s0 = 0, s1 = 0, s2 = 0, s3 = 0;
#pragma unroll
    for (int s = 0; s < KS; ++s) {
        const float4 v = *(const float4*)&parts[((size_t)(s * 128 + o)) * NPOS + p4];
        s0 += v.x; s1 += v.y; s2 += v.z; s3 += v.w;
    }
    float bv = ob[o];
    s0 += bv; s1 += bv; s2 += bv; s3 += bv;
    if (o >= 81) {
        s0 = 1.f / (1.f + __expf(-s0));
        s1 = 1.f / (1.f + __expf(-s1));
        s2 = 1.f / (1.f + __expf(-s2));
        s3 = 1.f / (1.f + __expf(-s3));
    }
    *(float4*)&dbuf[(size_t)o * NPOS + p4] = make_float4(s0, s1, s2, s3);
}

// ---------------- combine deform partials -> relu bf16, transposed into XpB interior ----------------
__global__ __launch_bounds__(256) void dcombine_h(const float* __restrict__ parts,
                                                  const float* __restrict__ bias,
                                                  unsigned short* __restrict__ XpB) {
    __shared__ unsigned short T[64 * 66];
    int p0 = blockIdx.x * 64, o0 = blockIdx.y * 64;
    int t = threadIdx.x;
    int pl = t & 63, og = t >> 6;
#pragma unroll 4
    for (int j = 0; j < 16; ++j) {
        int ol = og * 16 + j;
        float s = 0.f;
#pragma unroll
        for (int sp = 0; sp < KS; ++sp)
            s += parts[((size_t)(sp * 256 + o0 + ol)) * NPOS + p0 + pl];
        s += bias[o0 + ol];
        T[ol * 66 + pl] = f2bf(fmaxf(s, 0.f));
    }
    __syncthreads();
    int c = t & 63, pr = t >> 6;
#pragma unroll 4
    for (int j = 0; j < 16; ++j) {
        int pl2 = j * 4 + pr;
        int pg = p0 + pl2;
        int zz = pg >> 10, yy = (pg >> 5) & 31, xv = pg & 31;
        int row = (zz + 1) * XP_SZ + (yy + 1) * XP_SY + xv + 1;
        XpB[(size_t)row * 256 + o0 + c] = T[c * 66 + pl2];
    }
}

// ---------------- final combine -> fp32 o-major output (bias only) ----------------
__global__ __launch_bounds__(256) void dcombine_out(const float* __restrict__ parts,
                                                    const float* __restrict__ bias,
                                                    float* __restrict__ out) {
    int b = blockIdx.x;                 // 256*8
    int o = b >> 3;
    int p4 = ((b & 7) * 256 + threadIdx.x) * 4;
    float s0 = 0, s1 = 0, s2 = 0, s3 = 0;
#pragma unroll
    for (int s = 0; s < KS; ++s) {
        const float4 v = *(const float4*)&parts[((size_t)(s * 256 + o)) * NPOS + p4];
        s0 += v.x; s1 += v.y; s2 += v.z; s3 += v.w;
    }
    float bv = bias[o];
    *(float4*)&out[(size_t)o * NPOS + p4] = make_float4(s0 + bv, s1 + bv, s2 + bv, s3 + bv);
}

// ---------------- host orchestration ----------------
extern "C" void kernel_launch(void* const* d_in, const int* in_sizes, int n_in,
                              void* d_out, int out_size, void* d_ws, size_t ws_size,
                              hipStream_t stream) {
    const float* x      = (const float*)d_in[0];
    const float* ow1    = (const float*)d_in[1];
    const float* ob1    = (const float*)d_in[2];
    const float* w1     = (const float*)d_in[3];
    const float* b1     = (const float*)d_in[4];
    const float* ow2    = (const float*)d_in[5];
    const float* ob2    = (const float*)d_in[6];
    const float* w2     = (const float*)d_in[7];
    const float* b2     = (const float*)d_in[8];
    const float* ow3    = (const float*)d_in[9];
    const float* ob3    = (const float*)d_in[10];
    const float* w3     = (const float*)d_in[11];
    const float* b3     = (const float*)d_in[12];
    const float* defo_w = (const float*)d_in[13];
    const float* defo_b = (const float*)d_in[14];
    const float* c3d_w  = (const float*)d_in[15];
    const float* c3d_b  = (const float*)d_in[16];
    float* out = (float*)d_out;

    // workspace carve-up (~104 MB)
    unsigned short* XpA    = (unsigned short*)d_ws;          // 2,959,360 us
    unsigned short* XpB    = XpA + (size_t)XP_ROWS * 256;    // 2,959,360 us (adjacent for zero_k)
    unsigned short* wtoff  = XpB + (size_t)XP_ROWS * 256;    // 4*128*6912 us
    unsigned short* wtmain = wtoff + (size_t)4 * 128 * KTOT; // 4*256*6912 us
    float* dbufp = (float*)(wtmain + (size_t)4 * 256 * KTOT);// 108*8192 fp32
    float* parts = dbufp + (size_t)108 * NPOS;               // KS*256*8192 fp32 = 67 MB

    const dim3 blk(256);
    const dim3 gG(128, KS);

    zero_k<<<2890, blk, 0, stream>>>(XpA);                   // zeros XpA + XpB
    pad_x_t<<<256, blk, 0, stream>>>(x, XpA);
    wtrans_all<<<1536, blk, 0, stream>>>(ow1, ow2, ow3, defo_w, w1, w2, w3, c3d_w, wtoff, wtmain);

    const float* cbias[4] = {ob1, ob2, ob3, defo_b};
    const float* dbias[4] = {b1, b2, b3, c3d_b};

    for (int L = 0; L < 4; ++L) {
        const unsigned short* featConv = (L == 0) ? XpA : XpB;          // conv input = h_{L-1}
        const unsigned short* featDef  = (L == 3) ? XpA : featConv;     // final deform samples original x
        fgemm<false><<<gG, blk, 0, stream>>>(featConv, wtoff + (size_t)L * 128 * KTOT, nullptr, parts);
        ccombine<<<864, blk, 0, stream>>>(parts, cbias[L], dbufp);
        fgemm<true><<<gG, blk, 0, stream>>>(featDef, wtmain + (size_t)L * 256 * KTOT, dbufp, parts);
        if (L < 3) dcombine_h<<<dim3(128, 4), blk, 0, stream>>>(parts, dbias[L], XpB);
        else       dcombine_out<<<2048, blk, 0, stream>>>(parts, dbias[L], out);
    }
}

// Round 8
// 835.162 us; speedup vs baseline: 2.0482x; 1.0323x over previous
//
#include <hip/hip_runtime.h>
#include <cstdint>

// ---------------- problem constants ----------------
#define NPOS 8192              // 8*32*32 spatial positions
#define KTOT 6912              // 27 taps * 256 channels
#define XP_ROWS 11560          // 10*34*34 padded spatial rows
#define XP_SY 34
#define XP_SZ 1156             // 34*34
#define KS 6                   // K-splits
#define KSL 1152               // KTOT/KS -> 36 chunks of 32
#define NTAPS 6                // taps spanned per K-split (<=5, alloc 6)

typedef float  facc_t __attribute__((ext_vector_type(4)));
typedef short  bf8_t  __attribute__((ext_vector_type(8)));   // MFMA bf16 frag (4 VGPRs)
typedef unsigned short ub8_t __attribute__((ext_vector_type(8)));
typedef float  f4_t   __attribute__((ext_vector_type(4)));

__device__ __forceinline__ unsigned short f2bf(float f) {
    unsigned u = __float_as_uint(f);
    u = (u + 0x7FFFu + ((u >> 16) & 1u)) >> 16;   // RNE
    return (unsigned short)u;
}
__device__ __forceinline__ float bf2f(unsigned short u) {
    return __uint_as_float(((unsigned)u) << 16);
}

// async global->LDS, 16B/lane, LDS dest = wave-uniform base + lane*16 (no dest VGPRs)
__device__ __forceinline__ void gl_lds16(const unsigned short* g, unsigned short* l) {
    __builtin_amdgcn_global_load_lds(
        (const __attribute__((address_space(1))) unsigned int*)g,
        (__attribute__((address_space(3))) unsigned int*)l, 16, 0, 0);
}

// ---------------- zero XpA+XpB (adjacent, 2*2,959,360 us) ----------------
__global__ __launch_bounds__(256) void zero_k(unsigned short* __restrict__ dst) {
    ub8_t zz = {0,0,0,0,0,0,0,0};
    *(ub8_t*)&dst[((size_t)blockIdx.x * 256 + threadIdx.x) * 8] = zz;
}

// ---------------- pad x: fp32 c-major (256,8192) -> interior of XpA[row][256] bf16 ----------------
__global__ __launch_bounds__(256) void pad_x_t(const float* __restrict__ x,
                                               unsigned short* __restrict__ XpA) {
    __shared__ unsigned short T[256 * 33];
    int b = blockIdx.x;
    int z = b >> 5, y = b & 31;
    int t = threadIdx.x;
    int c8 = t >> 5, xv = t & 31;
#pragma unroll 4
    for (int i = 0; i < 32; ++i) {
        int c = i * 8 + c8;
        T[c * 33 + xv] = f2bf(x[c * NPOS + (z << 10) + (y << 5) + xv]);
    }
    __syncthreads();
    int rowb = ((z + 1) * XP_SZ + (y + 1) * XP_SY + 1) * 256;
#pragma unroll 4
    for (int j = 0; j < 32; ++j) {
        XpA[rowb + j * 256 + t] = T[t * 33 + j];
    }
}

// ---------------- all 8 weight transposes in one launch ----------------
__global__ __launch_bounds__(256) void wtrans_all(
    const float* __restrict__ o1, const float* __restrict__ o2,
    const float* __restrict__ o3, const float* __restrict__ o4,
    const float* __restrict__ m1, const float* __restrict__ m2,
    const float* __restrict__ m3, const float* __restrict__ m4,
    unsigned short* __restrict__ wtoff, unsigned short* __restrict__ wtmain) {
    __shared__ float T[6912];
    int b = blockIdx.x, t = threadIdx.x;
    const float* src; unsigned short* dst; int o, O;
    if (b < 512) {
        int L = b >> 7; o = b & 127; O = 108;
        src = (L == 0) ? o1 : (L == 1) ? o2 : (L == 2) ? o3 : o4;
        dst = wtoff + ((size_t)(L * 128 + o)) * KTOT;
    } else {
        int b2 = b - 512;
        int L = b2 >> 8; o = b2 & 255; O = 256;
        src = (L == 0) ? m1 : (L == 1) ? m2 : (L == 2) ? m3 : m4;
        dst = wtmain + ((size_t)(L * 256 + o)) * KTOT;
    }
    if (o < O) {
#pragma unroll 3
        for (int i = 0; i < 27; ++i) T[i * 256 + t] = src[(size_t)o * KTOT + i * 256 + t];
        __syncthreads();
#pragma unroll 3
        for (int i = 0; i < 27; ++i) {
            int kc = i * 256 + t;
            int c = kc & 255, k = kc >> 8;
            dst[kc] = f2bf(T[c * 27 + k]);
        }
    } else {
#pragma unroll 3
        for (int i = 0; i < 27; ++i) dst[i * 256 + t] = 0;
    }
}

// ---------------- fused implicit GEMM, BK=32, K-split partials ----------------
// DEFORM chunk pipeline (2 barriers): combine(n)->Bs; [X]; issue async gathers(n+1);
// MFMA(n); [Y: vmcnt drain]. Cbuf j-rotated so combine reads are bank-conflict-free.
// Tap tables (row index + 8 corner weights per p) precomputed once in LDS.
template<bool DEFORM>
__global__ __launch_bounds__(256, 3)
void fgemm(const unsigned short* __restrict__ Xp,
           const unsigned short* __restrict__ wt,   // [O][KTOT] bf16
           const float* __restrict__ dbuf,          // [108][8192] (DEFORM only)
           float* __restrict__ parts) {
    constexpr int O   = DEFORM ? 256 : 128;
    constexpr int PWN = DEFORM ? 4 : 2;             // p-frags per wave
    constexpr int NCH = KSL / 32;                   // 36
    __shared__ unsigned short Cbuf[DEFORM ? 16384 : 1] __attribute__((aligned(16)));  // 32 KB
    __shared__ unsigned short Bs[64 * 32] __attribute__((aligned(16)));               // 4 KB
    __shared__ int   rowtab[DEFORM ? (NTAPS * 64) : 1];
    __shared__ float cwtab[DEFORM ? (NTAPS * 512) : 1];

    const int t = threadIdx.x;
    const int wave = t >> 6, lane = t & 63;
    const int q = lane >> 4, r = lane & 15;
    const int pbase = blockIdx.x * 64;
    const int ks = blockIdx.y;
    const int kstart = ks * KSL;
    const int k0 = kstart >> 8;

    const int obw = DEFORM ? (wave * 64) : ((wave >> 1) * 64);
    const int pfb = DEFORM ? 0 : ((wave & 1) * 32);

    // combine/conv-staging coords: thread -> (pl = t>>2, channel group cg = t&3)
    const int pl = t >> 2;
    const int cg = t & 3;
    const int p = pbase + pl;
    const int z = p >> 10, y = (p >> 5) & 31, xx = p & 31;
    const int bswr = pl * 32 + ((cg ^ (pl & 3)) << 3);   // Bs write slot (shorts)

    // deform async-staging coords: LDS slot(i,t) fixed; lane stages corner sj = (field - p&7)&7
    const int sphi  = t >> 5;            // p = i*8 + sphi
    const int sfld  = (t >> 2) & 7;      // stored field
    const int sj    = (sfld - sphi) & 7; // actual corner (j-rotation swizzle)
    const int squad = t & 3;
    const int sroff = ((sj >> 2) & 1) * XP_SZ + ((sj >> 1) & 1) * XP_SY + (sj & 1);

    facc_t acc[4][PWN];
#pragma unroll
    for (int i = 0; i < 4; ++i)
#pragma unroll
        for (int ip = 0; ip < PWN; ++ip) acc[i][ip] = (facc_t){0.f, 0.f, 0.f, 0.f};

    if (DEFORM) {
        // ---- precompute ALL tap tables for this K-split (once) ----
        const int ntaps = ((kstart + KSL - 1) >> 8) - k0 + 1;   // <= 5
        for (int it = t; it < ntaps * 64; it += 256) {
            int s = it >> 6;
            int k = k0 + s;
            int pp = pbase + (it & 63);
            int zz2 = pp >> 10, yy2 = (pp >> 5) & 31, xx2 = pp & 31;
            const int kd = k / 9, kh = (k / 3) % 3, kw = k % 3;
            float od  = dbuf[(3 * k + 0) * NPOS + pp];
            float oh  = dbuf[(3 * k + 1) * NPOS + pp];
            float ow_ = dbuf[(3 * k + 2) * NPOS + pp];
            float m   = dbuf[(81 + k) * NPOS + pp];
            float cd = (float)(zz2 + kd - 1) + od;
            float ch = (float)(yy2 + kh - 1) + oh;
            float cx = (float)(xx2 + kw - 1) + ow_;
            float fdf = floorf(cd), fhf = floorf(ch), fwf = floorf(cx);
            float fd = cd - fdf, fh = ch - fhf, fw = cx - fwf;
            float wz0 = 1.f - fd, wz1 = fd;
            float wy0 = 1.f - fh, wy1 = fh;
            float wx0 = 1.f - fw, wx1 = fw;
            int id, ih, iw;
            if (fdf < -1.f || fdf >= 8.f)  { wz0 = 0.f; wz1 = 0.f; id = 0; } else id = (int)fdf;
            if (fhf < -1.f || fhf >= 32.f) { wy0 = 0.f; wy1 = 0.f; ih = 0; } else ih = (int)fhf;
            if (fwf < -1.f || fwf >= 32.f) { wx0 = 0.f; wx1 = 0.f; iw = 0; } else iw = (int)fwf;
            wz0 *= m; wz1 *= m;
            float w00 = wz0 * wy0, w01 = wz0 * wy1, w10 = wz1 * wy0, w11 = wz1 * wy1;
            rowtab[it] = (id + 1) * XP_SZ + (ih + 1) * XP_SY + (iw + 1);
            cwtab[it * 8 + 0] = w00 * wx0; cwtab[it * 8 + 1] = w00 * wx1;
            cwtab[it * 8 + 2] = w01 * wx0; cwtab[it * 8 + 3] = w01 * wx1;
            cwtab[it * 8 + 4] = w10 * wx0; cwtab[it * 8 + 5] = w10 * wx1;
            cwtab[it * 8 + 6] = w11 * wx0; cwtab[it * 8 + 7] = w11 * wx1;
        }
        __syncthreads();

        // ---- prologue: gathers for chunk 0 ----
        {
            const int c0 = kstart & 255;
            const int ts0 = 0;
#pragma unroll
            for (int i = 0; i < 8; ++i) {
                int row = rowtab[ts0 * 64 + i * 8 + sphi] + sroff;
                gl_lds16(Xp + (size_t)row * 256 + c0 + squad * 8,
                         &Cbuf[(i * 256 + (t & ~63)) * 8]);
            }
        }
        __syncthreads();   // vmcnt drain -> Cbuf[0] ready

        for (int n = 0; n < NCH; ++n) {
            const int kc0 = kstart + n * 32;
            const int tslot = (kc0 >> 8) - k0;
            // ---- combine Cbuf -> Bs (bank-conflict-free via f=(j+pl)&7 rotation) ----
            {
                const float* cwp = &cwtab[(tslot * 64 + pl) * 8];
                f4_t cw0 = *(const f4_t*)cwp;
                f4_t cw1 = *(const f4_t*)(cwp + 4);
                float av[8];
#pragma unroll
                for (int e = 0; e < 8; ++e) av[e] = 0.f;
                const int sbase = (pl >> 3) * 256 + (pl & 7) * 32 + cg;
#pragma unroll
                for (int j = 0; j < 8; ++j) {
                    int f = (j + (pl & 7)) & 7;
                    ub8_t v = *(const ub8_t*)&Cbuf[(sbase + f * 4) * 8];
                    float w = (j < 4) ? cw0[j] : cw1[j - 4];
#pragma unroll
                    for (int e = 0; e < 8; ++e) av[e] += w * bf2f(v[e]);
                }
                ub8_t pk;
#pragma unroll
                for (int e = 0; e < 8; ++e) pk[e] = f2bf(av[e]);
                *(ub8_t*)&Bs[bswr] = pk;
            }
            __syncthreads();   // X: Bs ready, Cbuf consumed

            // ---- issue async gathers for chunk n+1 (fly behind MFMA) ----
            if (n + 1 < NCH) {
                const int kc1 = kstart + (n + 1) * 32;
                const int c1 = kc1 & 255;
                const int ts1 = (kc1 >> 8) - k0;
#pragma unroll
                for (int i = 0; i < 8; ++i) {
                    int row = rowtab[ts1 * 64 + i * 8 + sphi] + sroff;
                    gl_lds16(Xp + (size_t)row * 256 + c1 + squad * 8,
                             &Cbuf[(i * 256 + (t & ~63)) * 8]);
                }
            }
            // ---- MFMA: A from global (L2-resident weights), B from Bs ----
#pragma unroll
            for (int i = 0; i < 4; ++i) {
                bf8_t a = *(const bf8_t*)&wt[(size_t)(obw + i * 16 + r) * KTOT + kc0 + q * 8];
#pragma unroll
                for (int ip = 0; ip < PWN; ++ip) {
                    int brow = ip * 16 + r;
                    bf8_t b = *(const bf8_t*)&Bs[brow * 32 + ((q ^ (brow & 3)) << 3)];
                    acc[i][ip] = __builtin_amdgcn_mfma_f32_16x16x32_bf16(a, b, acc[i][ip], 0, 0, 0);
                }
            }
            __syncthreads();   // Y: vmcnt drain (Cbuf[n+1] ready), Bs consumed
        }
    } else {
        // ---- conv: simple stage -> MFMA, 2 barriers/chunk ----
        for (int n = 0; n < NCH; ++n) {
            const int kc0 = kstart + n * 32;
            const int k = kc0 >> 8;
            const int c0 = kc0 & 255;
            const int kd = k / 9, kh = (k / 3) % 3, kw = k % 3;
            int row = (z + kd) * XP_SZ + (y + kh) * XP_SY + (xx + kw);
            ub8_t v = *(const ub8_t*)&Xp[(size_t)row * 256 + c0 + cg * 8];
            *(ub8_t*)&Bs[bswr] = v;
            __syncthreads();
#pragma unroll
            for (int i = 0; i < 4; ++i) {
                bf8_t a = *(const bf8_t*)&wt[(size_t)(obw + i * 16 + r) * KTOT + kc0 + q * 8];
#pragma unroll
                for (int ip = 0; ip < PWN; ++ip) {
                    int brow = pfb + ip * 16 + r;
                    bf8_t b = *(const bf8_t*)&Bs[brow * 32 + ((q ^ (brow & 3)) << 3)];
                    acc[i][ip] = __builtin_amdgcn_mfma_f32_16x16x32_bf16(a, b, acc[i][ip], 0, 0, 0);
                }
            }
            __syncthreads();
        }
    }

    // ---- epilogue: fp32 partials; C/D map row(o)=q*4+reg, col(p)=r [verified R1-R7] ----
    float* pp = parts + (size_t)ks * O * NPOS;
#pragma unroll
    for (int i = 0; i < 4; ++i)
#pragma unroll
        for (int ip = 0; ip < PWN; ++ip)
#pragma unroll
            for (int reg = 0; reg < 4; ++reg) {
                int o = obw + i * 16 + q * 4 + reg;
                int px = pbase + pfb + ip * 16 + r;
                pp[(size_t)o * NPOS + px] = acc[i][ip][reg];
            }
}

// ---------------- combine conv partials -> dbuf (bias + sigmoid on o>=81) ----------------
__global__ __launch_bounds__(256) void ccombine(const float* __restrict__ parts,
                                                const float* __restrict__ ob,
                                                float* __restrict__ dbuf) {
    int b = blockIdx.x;                 // 108*8
    int o = b >> 3;
    int p4 = ((b & 7) * 256 + threadIdx.x) * 4;
    float s0 = 0, s1 = 0, s2 = 0, s3 = 0;
#pragma unroll
    for (int s = 0; s < KS; ++s) {
        const float4 v = *(const float4*)&parts[((size_t)(s * 128 + o)) * NPOS + p4];
        s0 += v.x; s1 += v.y; s2 += v.z; s3 += v.w;
    }
    float bv = ob[o];
    s0 += bv; s1 += bv; s2 += bv; s3 += bv;
    if (o >= 81) {
        s0 = 1.f / (1.f + __expf(-s0));
        s1 = 1.f / (1.f + __expf(-s1));
        s2 = 1.f / (1.f + __expf(-s2));
        s3 = 1.f / (1.f + __expf(-s3));
    }
    *(float4*)&dbuf[(size_t)o * NPOS + p4] = make_float4(s0, s1, s2, s3);
}

// ---------------- combine deform partials -> relu bf16, transposed into XpB interior ----------------
__global__ __launch_bounds__(256) void dcombine_h(const float* __restrict__ parts,
                                                  const float* __restrict__ bias,
                                                  unsigned short* __restrict__ XpB) {
    __shared__ unsigned short T[64 * 66];
    int p0 = blockIdx.x * 64, o0 = blockIdx.y * 64;
    int t = threadIdx.x;
    int pl = t & 63, og = t >> 6;
#pragma unroll 4
    for (int j = 0; j < 16; ++j) {
        int ol = og * 16 + j;
        float s = 0.f;
#pragma unroll
        for (int sp = 0; sp < KS; ++sp)
            s += parts[((size_t)(sp * 256 + o0 + ol)) * NPOS + p0 + pl];
        s += bias[o0 + ol];
        T[ol * 66 + pl] = f2bf(fmaxf(s, 0.f));
    }
    __syncthreads();
    int c = t & 63, pr = t >> 6;
#pragma unroll 4
    for (int j = 0; j < 16; ++j) {
        int pl2 = j * 4 + pr;
        int pg = p0 + pl2;
        int zz = pg >> 10, yy = (pg >> 5) & 31, xv = pg & 31;
        int row = (zz + 1) * XP_SZ + (yy + 1) * XP_SY + xv + 1;
        XpB[(size_t)row * 256 + o0 + c] = T[c * 66 + pl2];
    }
}

// ---------------- final combine -> fp32 o-major output (bias only) ----------------
__global__ __launch_bounds__(256) void dcombine_out(const float* __restrict__ parts,
                                                    const float* __restrict__ bias,
                                                    float* __restrict__ out) {
    int b = blockIdx.x;                 // 256*8
    int o = b >> 3;
    int p4 = ((b & 7) * 256 + threadIdx.x) * 4;
    float s0 = 0, s1 = 0, s2 = 0, s3 = 0;
#pragma unroll
    for (int s = 0; s < KS; ++s) {
        const float4 v = *(const float4*)&parts[((size_t)(s * 256 + o)) * NPOS + p4];
        s0 += v.x; s1 += v.y; s2 += v.z; s3 += v.w;
    }
    float bv = bias[o];
    *(float4*)&out[(size_t)o * NPOS + p4] = make_float4(s0 + bv, s1 + bv, s2 + bv, s3 + bv);
}

// ---------------- host orchestration ----------------
extern "C" void kernel_launch(void* const* d_in, const int* in_sizes, int n_in,
                              void* d_out, int out_size, void* d_ws, size_t ws_size,
                              hipStream_t stream) {
    const float* x      = (const float*)d_in[0];
    const float* ow1    = (const float*)d_in[1];
    const float* ob1    = (const float*)d_in[2];
    const float* w1     = (const float*)d_in[3];
    const float* b1     = (const float*)d_in[4];
    const float* ow2    = (const float*)d_in[5];
    const float* ob2    = (const float*)d_in[6];
    const float* w2     = (const float*)d_in[7];
    const float* b2     = (const float*)d_in[8];
    const float* ow3    = (const float*)d_in[9];
    const float* ob3    = (const float*)d_in[10];
    const float* w3     = (const float*)d_in[11];
    const float* b3     = (const float*)d_in[12];
    const float* defo_w = (const float*)d_in[13];
    const float* defo_b = (const float*)d_in[14];
    const float* c3d_w  = (const float*)d_in[15];
    const float* c3d_b  = (const float*)d_in[16];
    float* out = (float*)d_out;

    // workspace carve-up (~88 MB)
    unsigned short* XpA    = (unsigned short*)d_ws;          // 2,959,360 us
    unsigned short* XpB    = XpA + (size_t)XP_ROWS * 256;    // 2,959,360 us (adjacent for zero_k)
    unsigned short* wtoff  = XpB + (size_t)XP_ROWS * 256;    // 4*128*6912 us
    unsigned short* wtmain = wtoff + (size_t)4 * 128 * KTOT; // 4*256*6912 us
    float* dbufp = (float*)(wtmain + (size_t)4 * 256 * KTOT);// 108*8192 fp32
    float* parts = dbufp + (size_t)108 * NPOS;               // KS*256*8192 fp32 = 50.3 MB

    const dim3 blk(256);
    const dim3 gG(128, KS);

    zero_k<<<2890, blk, 0, stream>>>(XpA);                   // zeros XpA + XpB
    pad_x_t<<<256, blk, 0, stream>>>(x, XpA);
    wtrans_all<<<1536, blk, 0, stream>>>(ow1, ow2, ow3, defo_w, w1, w2, w3, c3d_w, wtoff, wtmain);

    const float* cbias[4] = {ob1, ob2, ob3, defo_b};
    const float* dbias[4] = {b1, b2, b3, c3d_b};

    for (int L = 0; L < 4; ++L) {
        const unsigned short* featConv = (L == 0) ? XpA : XpB;          // conv input = h_{L-1}
        const unsigned short* featDef  = (L == 3) ? XpA : featConv;     // final deform samples original x
        fgemm<false><<<gG, blk, 0, stream>>>(featConv, wtoff + (size_t)L * 128 * KTOT, nullptr, parts);
        ccombine<<<864, blk, 0, stream>>>(parts, cbias[L], dbufp);
        fgemm<true><<<gG, blk, 0, stream>>>(featDef, wtmain + (size_t)L * 256 * KTOT, dbufp, parts);
        if (L < 3) dcombine_h<<<dim3(128, 4), blk, 0, stream>>>(parts, dbias[L], XpB);
        else       dcombine_out<<<2048, blk, 0, stream>>>(parts, dbias[L], out);
    }
}